// Round 3
// baseline (383.326 us; speedup 1.0000x reference)
//
#include <hip/hip_runtime.h>
#include <math.h>

// ---------------- model constants ----------------
#define BATCH 65536
#define TB 64            // 4 waves x 16 rows, each wave fully independent

typedef _Float16 half4 __attribute__((ext_vector_type(4)));
typedef _Float16 half8 __attribute__((ext_vector_type(8)));
typedef float   floatx4 __attribute__((ext_vector_type(4)));

// per-wave LDS strides (halves). All are 8-half (16B) multiples, and
// stride/4 dwords ≡ 4 (mod 32) -> over 16 rows only 2-way bank alias (free).
#define SH 72     // hH: 64 cols + 8 pad
#define SM 136    // hM: 129 cols + 7 pad (pads zeroed once at start)
#define FS 72     // F : 64 k-slots/chunk + 8 pad

// packed-weight geometry (f16): [ Win | a0 | b0 | a1 | b1 ], each W[n][k]
#define WIN 2048          // W_in^T: 64 n x 32 k
#define KPA 576           // a: 64*8 spline + 64 silu
#define KPB 1280          // b: 136*8 spline (129 real) + 192 silu (129 real)
#define WA (144*KPA)      // 82944  (O=129 padded to 9 n-tiles)
#define WB (64*KPB)       // 81920
#define WTOT (WIN + 2*(WA+WB))   // 331776 halfs = 663552 B of d_ws

// ---------------------------------------------------------------------------
// setup: pack all weights f16.  spline slot k=8i+p -> ss*coef; silu slot -> sb
// ---------------------------------------------------------------------------
__global__ void setup_weights(
    const float* __restrict__ W_in,
    const float* __restrict__ c0a, const float* __restrict__ sb0a, const float* __restrict__ ss0a,
    const float* __restrict__ c0b, const float* __restrict__ sb0b, const float* __restrict__ ss0b,
    const float* __restrict__ c1a, const float* __restrict__ sb1a, const float* __restrict__ ss1a,
    const float* __restrict__ c1b, const float* __restrict__ sb1b, const float* __restrict__ ss1b,
    _Float16* __restrict__ wt) {
  int idx = blockIdx.x * 256 + threadIdx.x;
  if (idx >= WTOT) return;
  float v = 0.0f;
  if (idx < WIN) {                      // W_in^T[n][k], W_in is [32][64]
    int n = idx >> 5, k = idx & 31;
    v = W_in[k*64 + n];
  } else {
    int e2   = idx - WIN;
    int pair = (e2 >= WA + WB) ? 1 : 0;
    int e    = e2 - pair * (WA + WB);
    if (e < WA) {                       // a-type: I=64, O=129
      const float* coef = pair ? c1a : c0a;
      const float* sb   = pair ? sb1a : sb0a;
      const float* ss   = pair ? ss1a : ss0a;
      int n = e / KPA, k = e - n * KPA;
      if (n < 129) {
        if (k < 512) { int i = k >> 3, p = k & 7; v = ss[i*129+n] * coef[(i*129+n)*8 + p]; }
        else         { int i = k - 512;           v = sb[i*129+n]; }       // i < 64
      }
    } else {                            // b-type: I=129, O=64
      const float* coef = pair ? c1b : c0b;
      const float* sb   = pair ? sb1b : sb0b;
      const float* ss   = pair ? ss1b : ss0b;
      int eb = e - WA;
      int n = eb / KPB, k = eb - n * KPB;
      if (k < 1088) { int i = k >> 3, p = k & 7; if (i < 129) v = ss[i*64+n] * coef[(i*64+n)*8 + p]; }
      else          { int i = k - 1088;          if (i < 129) v = sb[i*64+n]; }
    }
  }
  wt[idx] = (_Float16)v;
}

// ---------------------------------------------------------------------------
// 8 cubic B-spline basis values, uniform knots t_j = 0.4j - 2.2 (j=0..11).
// Identical numerics to the validated round-1/2 kernels (absmax 0.0039).
// ---------------------------------------------------------------------------
__device__ __forceinline__ void feat8_store(_Float16* dst, float x) {
  float s  = (x + 2.2f) * 2.5f;
  float mf = floorf(s);
  int   m  = (int)mf;
  float u  = s - mf;
  float u2 = u*u, u3 = u2*u;
  float um = 1.0f - u;
  float w0 = um*um*um * (1.0f/6.0f);
  float w1 = (3.0f*u3 - 6.0f*u2 + 4.0f) * (1.0f/6.0f);
  float w2 = (-3.0f*u3 + 3.0f*u2 + 3.0f*u + 1.0f) * (1.0f/6.0f);
  float w3 = u3 * (1.0f/6.0f);
  half8 z;
  #pragma unroll
  for (int e = 0; e < 8; ++e) z[e] = (_Float16)0.0f;
  *(half8*)dst = z;                    // zero all 8 slots (one b128)
  if (m >= 0 && m <= 10) {             // same-wave DS ops are FIFO-ordered
    int j0 = m - 3;
    float w[4] = {w0, w1, w2, w3};
    #pragma unroll
    for (int q = 0; q < 4; ++q) {
      int p = j0 + q;
      if (p >= 0 && p < 8) dst[p] = (_Float16)w[q];
    }
  }
}

// ---------------------------------------------------------------------------
// one KAN layer, per-wave (16 rows), barrier-free.
// chunk = 8 inputs -> 64 k-slots -> 2 MFMA k-steps over NT n-tiles.
// A-frag: lane holds A[m=ln][k=kq*8..], read b128 from private F slice.
// B-frag: lane holds B[k=kq*8..][n=ln], read b128 from global wt (L1/L2).
// ---------------------------------------------------------------------------
template<int I, int O, int NT, int SPC, int SILC, int SIN, int SOUT, int KP>
__device__ __forceinline__ void kan_layer(
    const _Float16* __restrict__ hinw, _Float16* __restrict__ houtw,
    const _Float16* __restrict__ wt, const float* __restrict__ bias,
    _Float16* __restrict__ Fw, int lane) {
  const int ln = lane & 15;
  const int kq = lane >> 4;
  floatx4 acc[NT];
  #pragma unroll
  for (int j = 0; j < NT; ++j) acc[j] = (floatx4){0.f, 0.f, 0.f, 0.f};

  // ---- spline chunks ----
  #pragma unroll 1
  for (int c = 0; c < SPC; ++c) {
    #pragma unroll
    for (int jj = 0; jj < 2; ++jj) {
      int il = kq + jj*4;                       // local input 0..7
      int i  = c*8 + il;
      float xv = (i < I) ? (float)hinw[ln*SIN + i] : 0.0f;
      feat8_store(&Fw[ln*FS + il*8], xv);
    }
    #pragma unroll
    for (int kk = 0; kk < 2; ++kk) {
      half8 A = *(const half8*)&Fw[ln*FS + kk*32 + kq*8];
      #pragma unroll
      for (int j = 0; j < NT; ++j) {
        half8 B = *(const half8*)&wt[(j*16 + ln)*KP + (c*2 + kk)*32 + kq*8];
        acc[j] = __builtin_amdgcn_mfma_f32_16x16x32_f16(A, B, acc[j], 0, 0, 0);
      }
    }
  }

  // ---- silu chunks (64 slots each) ----
  #pragma unroll 1
  for (int sc = 0; sc < SILC; ++sc) {
    #pragma unroll
    for (int jj = 0; jj < 2; ++jj) {
      int oct = kq + jj*4;                      // 8-slot group 0..7
      int ib  = sc*64 + oct*8;
      half8 sv;
      if (ib < I) {                             // tail elements read zeroed pad
        half8 xv8 = *(const half8*)&hinw[ln*SIN + ib];
        #pragma unroll
        for (int e = 0; e < 8; ++e) {
          float xv = (float)xv8[e];
          sv[e] = (_Float16)(xv / (1.0f + __expf(-xv)));
        }
      } else {
        #pragma unroll
        for (int e = 0; e < 8; ++e) sv[e] = (_Float16)0.0f;
      }
      *(half8*)&Fw[ln*FS + oct*8] = sv;
    }
    #pragma unroll
    for (int kk = 0; kk < 2; ++kk) {
      half8 A = *(const half8*)&Fw[ln*FS + kk*32 + kq*8];
      #pragma unroll
      for (int j = 0; j < NT; ++j) {
        half8 B = *(const half8*)&wt[(j*16 + ln)*KP + (SPC*2 + sc*2 + kk)*32 + kq*8];
        acc[j] = __builtin_amdgcn_mfma_f32_16x16x32_f16(A, B, acc[j], 0, 0, 0);
      }
    }
  }

  // ---- epilogue: C/D col=lane&15, row=kq*4+r (m89-verified) ----
  #pragma unroll
  for (int j = 0; j < NT; ++j) {
    int col = j*16 + ln;
    if (col < O) {
      float bv = bias[col];
      #pragma unroll
      for (int r = 0; r < 4; ++r)
        houtw[(kq*4 + r)*SOUT + col] = (_Float16)(acc[j][r] + bv);
    }
  }
}

// ---------------------------------------------------------------------------
// fused forward, zero __syncthreads. LDS 35840 B -> 4 blocks/CU; grid 1024
// = exactly 4 blocks/CU (one generation, no tail).
// ---------------------------------------------------------------------------
extern "C" __global__ void __launch_bounds__(256, 4)
kan_forward(const float* __restrict__ x, const float* __restrict__ b_in,
            const float* __restrict__ W_out, const _Float16* __restrict__ wt,
            const float* __restrict__ bias0a, const float* __restrict__ bias0b,
            const float* __restrict__ bias1a, const float* __restrict__ bias1b,
            float* __restrict__ out) {
  __shared__ _Float16 hM[4][16*SM];
  __shared__ _Float16 hH[4][16*SH];
  __shared__ _Float16 F [4][16*FS];
  const int t    = threadIdx.x;
  const int wv   = t >> 6;
  const int lane = t & 63;
  const int ln   = lane & 15;
  const int kq   = lane >> 4;
  _Float16* hMw = hM[wv];
  _Float16* hHw = hH[wv];
  _Float16* Fw  = F [wv];
  const int rbase = blockIdx.x * TB + wv * 16;

  // zero hM pad cols 128..135 once (layer-b silu b128 tail reads them)
  if (lane < 16) {
    half8 z;
    #pragma unroll
    for (int e = 0; e < 8; ++e) z[e] = (_Float16)0.0f;
    *(half8*)&hMw[lane*SM + 128] = z;
  }

  // stage 0: x rows -> F (f16, k-slots 0..31)
  #pragma unroll
  for (int jj = 0; jj < 2; ++jj) {
    int sg = kq + jj*4;                     // float4 segment 0..7
    float4 v = *(const float4*)&x[(rbase + ln)*32 + sg*4];
    half4 h = { (_Float16)v.x, (_Float16)v.y, (_Float16)v.z, (_Float16)v.w };
    *(half4*)&Fw[ln*FS + sg*4] = h;
  }

  // stage 1: hH = relu(x @ W_in + b_in) — one MFMA k-step, 4 n-tiles
  {
    half8 A = *(const half8*)&Fw[ln*FS + kq*8];
    #pragma unroll
    for (int nt = 0; nt < 4; ++nt) {
      floatx4 acc = (floatx4){0.f, 0.f, 0.f, 0.f};
      half8 B = *(const half8*)&wt[(nt*16 + ln)*32 + kq*8];
      acc = __builtin_amdgcn_mfma_f32_16x16x32_f16(A, B, acc, 0, 0, 0);
      int col = nt*16 + ln;
      float bv = b_in[col];
      #pragma unroll
      for (int r = 0; r < 4; ++r)
        hHw[(kq*4 + r)*SH + col] = (_Float16)fmaxf(acc[r] + bv, 0.0f);
    }
  }

  kan_layer< 64,129,9, 8,1,SH,SM,KPA>(hHw, hMw, wt + WIN,             bias0a, Fw, lane);
  kan_layer<129, 64,4,17,3,SM,SH,KPB>(hMw, hHw, wt + WIN + WA,        bias0b, Fw, lane);
  kan_layer< 64,129,9, 8,1,SH,SM,KPA>(hHw, hMw, wt + WIN + WA + WB,   bias1a, Fw, lane);
  kan_layer<129, 64,4,17,3,SM,SH,KPB>(hMw, hHw, wt + WIN + 2*WA + WB, bias1b, Fw, lane);

  // final: out = sigmoid(hH @ W_out); kq-partials reduced by shuffle
  {
    float s = 0.0f;
    #pragma unroll
    for (int j = 0; j < 16; ++j)
      s = fmaf((float)hHw[ln*SH + kq*16 + j], W_out[kq*16 + j], s);
    s += __shfl_down(s, 32);
    s += __shfl_down(s, 16);
    if (lane < 16) out[rbase + ln] = 1.0f / (1.0f + __expf(-s));
  }
}

// ---------------------------------------------------------------------------
extern "C" void kernel_launch(void* const* d_in, const int* in_sizes, int n_in,
                              void* d_out, int out_size, void* d_ws, size_t ws_size,
                              hipStream_t stream) {
  const float* x     = (const float*)d_in[0];
  const float* W_in  = (const float*)d_in[1];
  const float* b_in  = (const float*)d_in[2];
  const float* W_out = (const float*)d_in[3];
  const float* c0a = (const float*)d_in[4];  const float* sb0a = (const float*)d_in[5];
  const float* ss0a= (const float*)d_in[6];  const float* bias0a=(const float*)d_in[7];
  const float* c0b = (const float*)d_in[8];  const float* sb0b = (const float*)d_in[9];
  const float* ss0b= (const float*)d_in[10]; const float* bias0b=(const float*)d_in[11];
  const float* c1a = (const float*)d_in[12]; const float* sb1a = (const float*)d_in[13];
  const float* ss1a= (const float*)d_in[14]; const float* bias1a=(const float*)d_in[15];
  const float* c1b = (const float*)d_in[16]; const float* sb1b = (const float*)d_in[17];
  const float* ss1b= (const float*)d_in[18]; const float* bias1b=(const float*)d_in[19];
  float*    out = (float*)d_out;
  _Float16* wt  = (_Float16*)d_ws;       // 663,552 B scratch, repacked every call

  setup_weights<<<(WTOT + 255)/256, 256, 0, stream>>>(
      W_in, c0a, sb0a, ss0a, c0b, sb0b, ss0b,
      c1a, sb1a, ss1a, c1b, sb1b, ss1b, wt);

  kan_forward<<<BATCH/TB, 256, 0, stream>>>(
      x, b_in, W_out, wt, bias0a, bias0b, bias1a, bias1b, out);
}

// Round 4
// 348.384 us; speedup vs baseline: 1.1003x; 1.1003x over previous
//
#include <hip/hip_runtime.h>
#include <math.h>

// ---------------- model constants ----------------
#define BATCH 65536
#define TB 128           // 4 waves x 32 rows, each wave fully independent

typedef _Float16 half4 __attribute__((ext_vector_type(4)));
typedef _Float16 half8 __attribute__((ext_vector_type(8)));
typedef float   floatx4 __attribute__((ext_vector_type(4)));

// per-wave LDS strides (halves)
#define SH 72     // hH: 64 cols + 8 pad
#define SM 136    // hM: 129 cols + 7 pad (pads zeroed once at start)
#define FS 72     // F : 64 k-slots/chunk + 8 pad

// packed-weight geometry (f16), FRAGMENT-ORDERED:
//   element (ks, nt, lane, j)  at  ((ks*NT + nt)*64 + lane)*8 + j
//   maps to  B[k = ks*32 + (lane>>4)*8 + j][n = nt*16 + (lane&15)]
// so a wave's B-frag load is base + lane*16B  -> one coalesced 1KB transaction.
#define WIN 2048          // stage1: 1 kstep x 4 ntiles x 512
#define KSA 18            // a: 576 k = 512 spline + 64 silu
#define KSB 40            // b: 1280 k = 1088 spline (129 real) + 192 silu (129 real)
#define WA (KSA*9*512)    // 82944
#define WB (KSB*4*512)    // 81920
#define WTOT (WIN + 2*(WA+WB))   // 331776 halfs = 663552 B of d_ws

// ---------------------------------------------------------------------------
// setup: pack all weights f16 in fragment order.
// spline slot k=8i+p -> ss*coef; silu slot -> sb; zero outside real I/O.
// ---------------------------------------------------------------------------
__global__ void setup_weights(
    const float* __restrict__ W_in,
    const float* __restrict__ c0a, const float* __restrict__ sb0a, const float* __restrict__ ss0a,
    const float* __restrict__ c0b, const float* __restrict__ sb0b, const float* __restrict__ ss0b,
    const float* __restrict__ c1a, const float* __restrict__ sb1a, const float* __restrict__ ss1a,
    const float* __restrict__ c1b, const float* __restrict__ sb1b, const float* __restrict__ ss1b,
    _Float16* __restrict__ wt) {
  int idx = blockIdx.x * 256 + threadIdx.x;
  if (idx >= WTOT) return;
  float v = 0.0f;
  if (idx < WIN) {                        // W_in: [32][64] -> frag order, 4 ntiles
    int nt = idx >> 9; int r = idx & 511; int l = r >> 3; int j = r & 7;
    int n = nt*16 + (l & 15);
    int k = (l >> 4)*8 + j;
    v = W_in[k*64 + n];
  } else {
    int e2   = idx - WIN;
    int pair = (e2 >= WA + WB) ? 1 : 0;
    int e    = e2 - pair * (WA + WB);
    if (e < WA) {                         // a-type: I=64, O=129 (9 ntiles)
      const float* coef = pair ? c1a : c0a;
      const float* sb   = pair ? sb1a : sb0a;
      const float* ss   = pair ? ss1a : ss0a;
      int ks = e / 4608; int r = e - ks*4608;
      int nt = r >> 9;   int q = r & 511;
      int l  = q >> 3;   int j = q & 7;
      int n  = nt*16 + (l & 15);
      int k  = ks*32 + (l >> 4)*8 + j;
      if (n < 129) {
        if (k < 512) { int i = k >> 3, p = k & 7; v = ss[i*129+n] * coef[(i*129+n)*8 + p]; }
        else         { int i = k - 512;           v = sb[i*129+n]; }     // i < 64
      }
    } else {                              // b-type: I=129, O=64 (4 ntiles)
      const float* coef = pair ? c1b : c0b;
      const float* sb   = pair ? sb1b : sb0b;
      const float* ss   = pair ? ss1b : ss0b;
      int eb = e - WA;
      int ks = eb >> 11; int r = eb & 2047;
      int nt = r >> 9;   int q = r & 511;
      int l  = q >> 3;   int j = q & 7;
      int n  = nt*16 + (l & 15);
      int k  = ks*32 + (l >> 4)*8 + j;
      if (k < 1088) { int i = k >> 3, p = k & 7; if (i < 129) v = ss[i*64+n] * coef[(i*64+n)*8 + p]; }
      else          { int i = k - 1088;          if (i < 129) v = sb[i*64+n]; }
    }
  }
  wt[idx] = (_Float16)v;
}

// ---------------------------------------------------------------------------
// 8 cubic B-spline basis values, uniform knots t_j = 0.4j - 2.2 (j=0..11).
// Branchless: same numerics as validated r1-r3 (absmax 0.0059).
// ---------------------------------------------------------------------------
__device__ __forceinline__ half8 feat8(float x) {
  float s  = (x + 2.2f) * 2.5f;
  float mf = floorf(s);
  int   m  = (int)mf;
  float u  = s - mf;
  float u2 = u*u, u3 = u2*u;
  float um = 1.0f - u;
  float w0 = um*um*um * (1.0f/6.0f);
  float w1 = (3.0f*u3 - 6.0f*u2 + 4.0f) * (1.0f/6.0f);
  float w2 = (-3.0f*u3 + 3.0f*u2 + 3.0f*u + 1.0f) * (1.0f/6.0f);
  float w3 = u3 * (1.0f/6.0f);
  bool valid = (m >= 0) && (m <= 10);
  if (!valid) { w0 = w1 = w2 = w3 = 0.0f; }
  int j0 = m - 3;
  half8 f;
  #pragma unroll
  for (int p = 0; p < 8; ++p) {
    int d = p - j0;
    float v = (d == 0) ? w0 : (d == 1) ? w1 : (d == 2) ? w2 : (d == 3) ? w3 : 0.0f;
    f[p] = (_Float16)v;
  }
  return f;
}

// ---------------------------------------------------------------------------
// one KAN layer, per-wave (32 rows = 2 m-tiles), barrier-free.
// chunk = 8 inputs -> 64 k-slots -> 2 MFMA k-steps over NT n-tiles x 2 m-tiles.
// A-frag: ds_read_b128 from private F slice. B-frag: coalesced b128 from wt.
// ---------------------------------------------------------------------------
template<int I, int O, int NT, int SPC, int SILC, int SIN, int SOUT>
__device__ __forceinline__ void kan_layer(
    const _Float16* __restrict__ hinw, _Float16* __restrict__ houtw,
    const _Float16* __restrict__ wt, const float* __restrict__ bias,
    _Float16* __restrict__ Fw, int lane) {
  const int ln = lane & 15;
  const int kq = lane >> 4;
  floatx4 acc[NT][2];
  #pragma unroll
  for (int j = 0; j < NT; ++j)
    #pragma unroll
    for (int mt = 0; mt < 2; ++mt) acc[j][mt] = (floatx4){0.f, 0.f, 0.f, 0.f};

  // ---- spline chunks ----
  #pragma unroll 1
  for (int c = 0; c < SPC; ++c) {
    #pragma unroll
    for (int jj = 0; jj < 4; ++jj) {
      int row = jj*8 + (lane >> 3);            // 0..31
      int il  = lane & 7;                      // local input 0..7
      int i   = c*8 + il;
      float xv = (i < I) ? (float)hinw[row*SIN + i] : 0.0f;
      *(half8*)&Fw[row*FS + il*8] = feat8(xv);
    }
    #pragma unroll
    for (int kk = 0; kk < 2; ++kk) {
      half8 A0 = *(const half8*)&Fw[ ln      *FS + kk*32 + kq*8];
      half8 A1 = *(const half8*)&Fw[(16 + ln)*FS + kk*32 + kq*8];
      #pragma unroll
      for (int j = 0; j < NT; ++j) {
        half8 B = *(const half8*)&wt[(((c*2 + kk)*NT + j) << 9) + lane*8];
        acc[j][0] = __builtin_amdgcn_mfma_f32_16x16x32_f16(A0, B, acc[j][0], 0, 0, 0);
        acc[j][1] = __builtin_amdgcn_mfma_f32_16x16x32_f16(A1, B, acc[j][1], 0, 0, 0);
      }
    }
  }

  // ---- silu chunks (64 k-slots each) ----
  #pragma unroll 1
  for (int sc = 0; sc < SILC; ++sc) {
    #pragma unroll
    for (int jj = 0; jj < 4; ++jj) {
      int row = jj*8 + (lane >> 3);
      int oct = lane & 7;
      int ib  = sc*64 + oct*8;
      half8 sv;
      if (ib < I) {                            // ib==128 reads zeroed pad cols
        half8 xv8 = *(const half8*)&hinw[row*SIN + ib];
        #pragma unroll
        for (int e = 0; e < 8; ++e) {
          float xv = (float)xv8[e];
          sv[e] = (_Float16)(xv / (1.0f + __expf(-xv)));
        }
      } else {
        #pragma unroll
        for (int e = 0; e < 8; ++e) sv[e] = (_Float16)0.0f;
      }
      *(half8*)&Fw[row*FS + oct*8] = sv;
    }
    #pragma unroll
    for (int kk = 0; kk < 2; ++kk) {
      half8 A0 = *(const half8*)&Fw[ ln      *FS + kk*32 + kq*8];
      half8 A1 = *(const half8*)&Fw[(16 + ln)*FS + kk*32 + kq*8];
      #pragma unroll
      for (int j = 0; j < NT; ++j) {
        half8 B = *(const half8*)&wt[((((SPC + sc)*2 + kk)*NT + j) << 9) + lane*8];
        acc[j][0] = __builtin_amdgcn_mfma_f32_16x16x32_f16(A0, B, acc[j][0], 0, 0, 0);
        acc[j][1] = __builtin_amdgcn_mfma_f32_16x16x32_f16(A1, B, acc[j][1], 0, 0, 0);
      }
    }
  }

  // ---- epilogue: C/D col=lane&15, row=kq*4+r (m89-verified) ----
  #pragma unroll
  for (int j = 0; j < NT; ++j) {
    int col = j*16 + ln;
    if (col < O) {
      float bv = bias[col];
      #pragma unroll
      for (int mt = 0; mt < 2; ++mt)
        #pragma unroll
        for (int r = 0; r < 4; ++r)
          houtw[(mt*16 + kq*4 + r)*SOUT + col] = (_Float16)(acc[j][mt][r] + bv);
    }
  }
}

// ---------------------------------------------------------------------------
// fused forward, zero __syncthreads. LDS 71680 B -> 2 blocks/CU; grid 512
// = exactly 2 blocks/CU (one generation, no tail).
// ---------------------------------------------------------------------------
extern "C" __global__ void __launch_bounds__(256, 2)
kan_forward(const float* __restrict__ x, const float* __restrict__ b_in,
            const float* __restrict__ W_out, const _Float16* __restrict__ wt,
            const float* __restrict__ bias0a, const float* __restrict__ bias0b,
            const float* __restrict__ bias1a, const float* __restrict__ bias1b,
            float* __restrict__ out) {
  __shared__ _Float16 hM[4][32*SM];
  __shared__ _Float16 hH[4][32*SH];
  __shared__ _Float16 F [4][32*FS];
  const int t    = threadIdx.x;
  const int wv   = t >> 6;
  const int lane = t & 63;
  const int ln   = lane & 15;
  const int kq   = lane >> 4;
  _Float16* hMw = hM[wv];
  _Float16* hHw = hH[wv];
  _Float16* Fw  = F [wv];
  const int rbase = blockIdx.x * TB + wv * 32;

  // zero hM pad cols 128..135 (layer-b silu b128 tail reads them)
  if (lane < 32) {
    half8 z;
    #pragma unroll
    for (int e = 0; e < 8; ++e) z[e] = (_Float16)0.0f;
    *(half8*)&hMw[lane*SM + 128] = z;
  }

  // stage 0: x rows (32x32 f32) -> F k-slots 0..31 (f16)
  #pragma unroll
  for (int q = 0; q < 4; ++q) {
    int row = lane >> 1;
    int seg = (lane & 1) + q*2;               // float4 segment 0..7
    float4 v = *(const float4*)&x[(rbase + row)*32 + seg*4];
    half4 h = { (_Float16)v.x, (_Float16)v.y, (_Float16)v.z, (_Float16)v.w };
    *(half4*)&Fw[row*FS + seg*4] = h;
  }

  // stage 1: hH = relu(x @ W_in + b_in) — one k-step, 4 n-tiles, 2 m-tiles
  {
    half8 A0 = *(const half8*)&Fw[ ln      *FS + kq*8];
    half8 A1 = *(const half8*)&Fw[(16 + ln)*FS + kq*8];
    #pragma unroll
    for (int nt = 0; nt < 4; ++nt) {
      floatx4 z = (floatx4){0.f, 0.f, 0.f, 0.f};
      half8 B = *(const half8*)&wt[(nt << 9) + lane*8];
      floatx4 a0 = __builtin_amdgcn_mfma_f32_16x16x32_f16(A0, B, z, 0, 0, 0);
      floatx4 a1 = __builtin_amdgcn_mfma_f32_16x16x32_f16(A1, B, z, 0, 0, 0);
      int col = nt*16 + ln;
      float bv = b_in[col];
      #pragma unroll
      for (int r = 0; r < 4; ++r) {
        hHw[(      kq*4 + r)*SH + col] = (_Float16)fmaxf(a0[r] + bv, 0.0f);
        hHw[(16 + kq*4 + r)*SH + col] = (_Float16)fmaxf(a1[r] + bv, 0.0f);
      }
    }
  }

  kan_layer< 64,129,9, 8,1,SH,SM>(hHw, hMw, wt + WIN,             bias0a, Fw, lane);
  kan_layer<129, 64,4,17,3,SM,SH>(hMw, hHw, wt + WIN + WA,        bias0b, Fw, lane);
  kan_layer< 64,129,9, 8,1,SH,SM>(hHw, hMw, wt + WIN + WA + WB,   bias1a, Fw, lane);
  kan_layer<129, 64,4,17,3,SM,SH>(hMw, hHw, wt + WIN + 2*WA + WB, bias1b, Fw, lane);

  // final: out = sigmoid(hH @ W_out); two col-halves reduced by shuffle
  {
    int row = lane & 31;
    int kh  = lane >> 5;
    float s = 0.0f;
    #pragma unroll
    for (int j = 0; j < 32; ++j)
      s = fmaf((float)hHw[row*SH + kh*32 + j], W_out[kh*32 + j], s);
    s += __shfl_down(s, 32);
    if (lane < 32) out[rbase + row] = 1.0f / (1.0f + __expf(-s));
  }
}

// ---------------------------------------------------------------------------
extern "C" void kernel_launch(void* const* d_in, const int* in_sizes, int n_in,
                              void* d_out, int out_size, void* d_ws, size_t ws_size,
                              hipStream_t stream) {
  const float* x     = (const float*)d_in[0];
  const float* W_in  = (const float*)d_in[1];
  const float* b_in  = (const float*)d_in[2];
  const float* W_out = (const float*)d_in[3];
  const float* c0a = (const float*)d_in[4];  const float* sb0a = (const float*)d_in[5];
  const float* ss0a= (const float*)d_in[6];  const float* bias0a=(const float*)d_in[7];
  const float* c0b = (const float*)d_in[8];  const float* sb0b = (const float*)d_in[9];
  const float* ss0b= (const float*)d_in[10]; const float* bias0b=(const float*)d_in[11];
  const float* c1a = (const float*)d_in[12]; const float* sb1a = (const float*)d_in[13];
  const float* ss1a= (const float*)d_in[14]; const float* bias1a=(const float*)d_in[15];
  const float* c1b = (const float*)d_in[16]; const float* sb1b = (const float*)d_in[17];
  const float* ss1b= (const float*)d_in[18]; const float* bias1b=(const float*)d_in[19];
  float*    out = (float*)d_out;
  _Float16* wt  = (_Float16*)d_ws;       // 663,552 B scratch, repacked every call

  setup_weights<<<(WTOT + 255)/256, 256, 0, stream>>>(
      W_in, c0a, sb0a, ss0a, c0b, sb0b, ss0b,
      c1a, sb1a, ss1a, c1b, sb1b, ss1b, wt);

  kan_forward<<<BATCH/TB, 256, 0, stream>>>(
      x, b_in, W_out, wt, bias0a, bias0b, bias1a, bias1b, out);
}

// Round 5
// 188.336 us; speedup vs baseline: 2.0353x; 1.8498x over previous
//
#include <hip/hip_runtime.h>
#include <math.h>
#include <stdint.h>

// ---------------- model constants ----------------
#define BATCH 65536
#define TB 64            // 4 waves x 16 rows, each wave fully independent

typedef _Float16 half8 __attribute__((ext_vector_type(8)));
typedef float   floatx4 __attribute__((ext_vector_type(4)));

// per-wave LDS strides (halves)
#define SH 68            // hH: 64 cols + 4 pad  (34 dwords ≡ 2 mod 32: conflict-free)
#define SM 130           // hM: 129 cols + 1     (65 dwords ≡ 1 mod 32: conflict-free)
#define HM_SLICE (16*SM + 64)   // +64 halves zeroed tail pad (b128/scalar overruns)

// packed-weight geometry (f16), FRAGMENT-ORDERED:
//   element (ks, nt, lane, j) at ((ks*NT + nt)*512) + lane*8 + j
//   maps to B[k = ks*32 + (lane>>4)*8 + j][n = nt*16 + (lane&15)]
// -> a wave's B-frag load is base + lane*16B: one coalesced 1KB transaction.
#define WIN 2048          // stage1: 1 kstep x 4 ntiles x 512
#define KSA 18            // a: 16 spline ksteps (512 k) + 2 silu (64)
#define KSB 39            // b: 34 spline ksteps (1088 k, 129 real) + 5 silu (160, 129 real)
#define WA (KSA*9*512)    // 82944
#define WB (KSB*4*512)    // 79872
#define WTOT (WIN + 2*(WA+WB))   // 327680 halfs = 655360 B of d_ws

// ---------------------------------------------------------------------------
// setup: pack all weights f16 in fragment order.
// spline slot k=8i+p -> ss*coef; silu slot -> sb; zero outside real I/O.
// ---------------------------------------------------------------------------
__global__ void setup_weights(
    const float* __restrict__ W_in,
    const float* __restrict__ c0a, const float* __restrict__ sb0a, const float* __restrict__ ss0a,
    const float* __restrict__ c0b, const float* __restrict__ sb0b, const float* __restrict__ ss0b,
    const float* __restrict__ c1a, const float* __restrict__ sb1a, const float* __restrict__ ss1a,
    const float* __restrict__ c1b, const float* __restrict__ sb1b, const float* __restrict__ ss1b,
    _Float16* __restrict__ wt) {
  int idx = blockIdx.x * 256 + threadIdx.x;
  if (idx >= WTOT) return;
  float v = 0.0f;
  if (idx < WIN) {                        // W_in: [32][64] -> frag order, 4 ntiles
    int nt = idx >> 9; int r = idx & 511; int l = r >> 3; int j = r & 7;
    int n = nt*16 + (l & 15);
    int k = (l >> 4)*8 + j;
    v = W_in[k*64 + n];
  } else {
    int e2   = idx - WIN;
    int pair = (e2 >= WA + WB) ? 1 : 0;
    int e    = e2 - pair * (WA + WB);
    if (e < WA) {                         // a-type: I=64, O=129 (9 ntiles)
      const float* coef = pair ? c1a : c0a;
      const float* sb   = pair ? sb1a : sb0a;
      const float* ss   = pair ? ss1a : ss0a;
      int ks = e / 4608; int r = e - ks*4608;
      int nt = r >> 9;   int q = r & 511;
      int l  = q >> 3;   int j = q & 7;
      int n  = nt*16 + (l & 15);
      int k  = ks*32 + (l >> 4)*8 + j;
      if (n < 129) {
        if (k < 512) { int i = k >> 3, p = k & 7; v = ss[i*129+n] * coef[(i*129+n)*8 + p]; }
        else         { int i = k - 512;           v = sb[i*129+n]; }     // i < 64
      }
    } else {                              // b-type: I=129, O=64 (4 ntiles)
      const float* coef = pair ? c1b : c0b;
      const float* sb   = pair ? sb1b : sb0b;
      const float* ss   = pair ? ss1b : ss0b;
      int eb = e - WA;
      int ks = eb >> 11; int r = eb & 2047;
      int nt = r >> 9;   int q = r & 511;
      int l  = q >> 3;   int j = q & 7;
      int n  = nt*16 + (l & 15);
      int k  = ks*32 + (l >> 4)*8 + j;
      if (k < 1088) { int i = k >> 3, p = k & 7; if (i < 129) v = ss[i*64+n] * coef[(i*64+n)*8 + p]; }
      else          { int i = k - 1088;          if (i < 129) v = sb[i*64+n]; }
    }
  }
  wt[idx] = (_Float16)v;
}

// ---------------------------------------------------------------------------
// feat8: the 8 B-spline basis values of x as a ready A-fragment (half8).
// Uniform knots t_j = 0.4j - 2.2 (j=0..11), same math as validated r1-r4.
// Placement via 128-bit funnel shift: pack {w0..w3} f16 in a u64, shift left
// by 16*(m-3) bits (negative = right). Out-of-window slots drop = reference's
// NB=8 truncation; invalid m (outside [-2.2,2.2)) -> all zero.
// ---------------------------------------------------------------------------
__device__ __forceinline__ half8 feat8(float x) {
  float s  = (x + 2.2f) * 2.5f;
  float mf = floorf(s);
  int   m  = (int)mf;
  float u  = s - mf;
  float t  = 1.0f - u;
  float u2 = u*u;
  float w0 = t*t*t * (1.0f/6.0f);
  float w3 = u2*u * (1.0f/6.0f);
  float w1 = fmaf(u2, fmaf(0.5f, u, -1.0f), 2.0f/3.0f);   // (3u^3-6u^2+4)/6
  float w2 = 1.0f - w0 - w1 - w3;                          // partition of unity
  union { _Float16 h[4]; uint64_t u; } P;
  P.h[0] = (_Float16)w0; P.h[1] = (_Float16)w1;
  P.h[2] = (_Float16)w2; P.h[3] = (_Float16)w3;
  uint64_t w01 = (m >= 0 && m <= 10) ? P.u : 0ull;
  int sh = (m - 3) * 16;                                   // bits; [-48, 112] when valid
  uint64_t q0 = (sh >= 0) ? ((sh < 64) ? (w01 << sh) : 0ull) : (w01 >> (-sh));
  uint64_t q1 = (sh >= 64) ? (w01 << (sh - 64))
                           : ((sh > 0) ? (w01 >> (64 - sh)) : 0ull);
  union { uint64_t q[2]; half8 h; } R;
  R.q[0] = q0; R.q[1] = q1;
  return R.h;
}

// ---------------------------------------------------------------------------
// one KAN layer, per-wave (16 rows = 1 m-tile), barrier-free, NO feature LDS:
// lane (ln,kq) computes its A-fragment in registers (feat8 of row ln, input
// i=4*ks+kq for spline steps; 8 silus of row ln, cols kq*8.. for silu steps).
// B-frags: coalesced b128 from fragment-ordered wt (L1/L2 resident).
// ---------------------------------------------------------------------------
template<int KSPL, int KSIL, int NT, int SIN, int O, int SOUT>
__device__ __forceinline__ void kan_layer(
    const _Float16* __restrict__ hinw, _Float16* __restrict__ houtw,
    const _Float16* __restrict__ wt, const float* __restrict__ bias, int lane) {
  const int ln = lane & 15;
  const int kq = lane >> 4;
  floatx4 acc[NT];
  #pragma unroll
  for (int j = 0; j < NT; ++j) acc[j] = (floatx4){0.f, 0.f, 0.f, 0.f};

  // ---- spline k-steps: input i = ks*4 + kq (reads past real I hit zeroed
  // pad / next-row data; their weights are zero) ----
  #pragma unroll 2
  for (int ks = 0; ks < KSPL; ++ks) {
    float xv = (float)hinw[ln*SIN + ks*4 + kq];
    half8 A = feat8(xv);
    #pragma unroll
    for (int j = 0; j < NT; ++j) {
      half8 B = *(const half8*)&wt[((ks*NT + j) << 9) + lane*8];
      acc[j] = __builtin_amdgcn_mfma_f32_16x16x32_f16(A, B, acc[j], 0, 0, 0);
    }
  }

  // ---- silu k-steps: slots = silu(h[ln][sk*32+kq*8 .. +7]) ----
  #pragma unroll 2
  for (int sk = 0; sk < KSIL; ++sk) {
    half8 h8 = *(const half8*)&hinw[ln*SIN + sk*32 + kq*8];
    half8 A;
    #pragma unroll
    for (int e = 0; e < 8; ++e) {
      float xv = (float)h8[e];
      A[e] = (_Float16)(xv / (1.0f + __expf(-xv)));
    }
    #pragma unroll
    for (int j = 0; j < NT; ++j) {
      half8 B = *(const half8*)&wt[(((KSPL + sk)*NT + j) << 9) + lane*8];
      acc[j] = __builtin_amdgcn_mfma_f32_16x16x32_f16(A, B, acc[j], 0, 0, 0);
    }
  }

  // ---- epilogue: C/D col=lane&15, row=kq*4+r (m89-verified) ----
  #pragma unroll
  for (int j = 0; j < NT; ++j) {
    int col = j*16 + ln;
    if (col < O) {
      float bv = bias[col];
      #pragma unroll
      for (int r = 0; r < 4; ++r)
        houtw[(kq*4 + r)*SOUT + col] = (_Float16)(acc[j][r] + bv);
    }
  }
}

// ---------------------------------------------------------------------------
// fused forward, zero __syncthreads, no feature staging.
// LDS = 4*(16*68 + 16*130+64)*2B = 25856 B; __launch_bounds__(256,4)
// -> 4 blocks/CU = 16 waves/CU; grid 1024 = exactly 4 blocks/CU.
// ---------------------------------------------------------------------------
extern "C" __global__ void __launch_bounds__(256, 4)
kan_forward(const float* __restrict__ x, const float* __restrict__ b_in,
            const float* __restrict__ W_out, const _Float16* __restrict__ wt,
            const float* __restrict__ bias0a, const float* __restrict__ bias0b,
            const float* __restrict__ bias1a, const float* __restrict__ bias1b,
            float* __restrict__ out) {
  __shared__ _Float16 hM[4][HM_SLICE];
  __shared__ _Float16 hH[4][16*SH];
  const int t    = threadIdx.x;
  const int wv   = t >> 6;
  const int lane = t & 63;
  const int ln   = lane & 15;
  const int kq   = lane >> 4;
  _Float16* hMw = hM[wv];
  _Float16* hHw = hH[wv];
  const int rbase = blockIdx.x * TB + wv * 16;

  // zero the hM spots that padded spline/silu reads can touch with garbage:
  // col 129 of each row, and the 64-half tail pad after row 15.
  hMw[16*SM + lane] = (_Float16)0.0f;
  if (lane < 16) hMw[lane*SM + 129] = (_Float16)0.0f;

  // stage 1: hH = relu(x @ W_in + b_in). A-frag straight from global x.
  {
    const float* xr = &x[(rbase + ln)*32 + kq*8];
    float4 v0 = *(const float4*)&xr[0];
    float4 v1 = *(const float4*)&xr[4];
    half8 A = { (_Float16)v0.x, (_Float16)v0.y, (_Float16)v0.z, (_Float16)v0.w,
                (_Float16)v1.x, (_Float16)v1.y, (_Float16)v1.z, (_Float16)v1.w };
    #pragma unroll
    for (int nt = 0; nt < 4; ++nt) {
      floatx4 z = (floatx4){0.f, 0.f, 0.f, 0.f};
      half8 B = *(const half8*)&wt[(nt << 9) + lane*8];
      floatx4 a = __builtin_amdgcn_mfma_f32_16x16x32_f16(A, B, z, 0, 0, 0);
      int col = nt*16 + ln;
      float bv = b_in[col];
      #pragma unroll
      for (int r = 0; r < 4; ++r)
        hHw[(kq*4 + r)*SH + col] = (_Float16)fmaxf(a[r] + bv, 0.0f);
    }
  }

  kan_layer<16,2,9,SH,129,SM>(hHw, hMw, wt + WIN,             bias0a, lane);
  kan_layer<34,5,4,SM, 64,SH>(hMw, hHw, wt + WIN + WA,        bias0b, lane);
  kan_layer<16,2,9,SH,129,SM>(hHw, hMw, wt + WIN + WA + WB,   bias1a, lane);
  kan_layer<34,5,4,SM, 64,SH>(hMw, hHw, wt + WIN + 2*WA + WB, bias1b, lane);

  // final: out = sigmoid(hH @ W_out); kq-partials reduced by shuffle
  {
    float s = 0.0f;
    #pragma unroll
    for (int j = 0; j < 16; ++j)
      s = fmaf((float)hHw[ln*SH + kq*16 + j], W_out[kq*16 + j], s);
    s += __shfl_down(s, 32);
    s += __shfl_down(s, 16);
    if (lane < 16) out[rbase + ln] = 1.0f / (1.0f + __expf(-s));
  }
}

// ---------------------------------------------------------------------------
extern "C" void kernel_launch(void* const* d_in, const int* in_sizes, int n_in,
                              void* d_out, int out_size, void* d_ws, size_t ws_size,
                              hipStream_t stream) {
  const float* x     = (const float*)d_in[0];
  const float* W_in  = (const float*)d_in[1];
  const float* b_in  = (const float*)d_in[2];
  const float* W_out = (const float*)d_in[3];
  const float* c0a = (const float*)d_in[4];  const float* sb0a = (const float*)d_in[5];
  const float* ss0a= (const float*)d_in[6];  const float* bias0a=(const float*)d_in[7];
  const float* c0b = (const float*)d_in[8];  const float* sb0b = (const float*)d_in[9];
  const float* ss0b= (const float*)d_in[10]; const float* bias0b=(const float*)d_in[11];
  const float* c1a = (const float*)d_in[12]; const float* sb1a = (const float*)d_in[13];
  const float* ss1a= (const float*)d_in[14]; const float* bias1a=(const float*)d_in[15];
  const float* c1b = (const float*)d_in[16]; const float* sb1b = (const float*)d_in[17];
  const float* ss1b= (const float*)d_in[18]; const float* bias1b=(const float*)d_in[19];
  float*    out = (float*)d_out;
  _Float16* wt  = (_Float16*)d_ws;       // 655,360 B scratch, repacked every call

  setup_weights<<<(WTOT + 255)/256, 256, 0, stream>>>(
      W_in, c0a, sb0a, ss0a, c0b, sb0b, ss0b,
      c1a, sb1a, ss1a, c1b, sb1b, ss1b, wt);

  kan_forward<<<BATCH/TB, 256, 0, stream>>>(
      x, b_in, W_out, wt, bias0a, bias0b, bias1a, bias1b, out);
}